// Round 2
// baseline (1039.203 us; speedup 1.0000x reference)
//
#include <hip/hip_runtime.h>
#include <hip/hip_bf16.h>

#define N_NODES 10000
#define NHID 128
#define NEDGE 320000

typedef float  float4_t  __attribute__((ext_vector_type(4)));
typedef short  short8    __attribute__((ext_vector_type(8)));

// ---------- detect edge_index dtype: flag=1 if int64 (odd words all zero) ----------
__global__ void k_detect(const int* __restrict__ ei32, int* __restrict__ flag) {
    __shared__ int s_or;
    if (threadIdx.x == 0) s_or = 0;
    __syncthreads();
    int v = ei32[2 * threadIdx.x + 1] | ei32[2 * ((int)threadIdx.x + 256) + 1];
    if (v) atomicOr(&s_or, 1);
    __syncthreads();
    if (threadIdx.x == 0) flag[0] = (s_or == 0) ? 1 : 0;
}

__device__ inline int edge_at(const int* __restrict__ ei, int mode, int idx) {
    // mode=1: buffer is int64 little-endian, values < 2^31 -> low word at 2*idx
    return mode ? ei[2 * idx] : ei[idx];
}

// ---------- degree init: deg[i] = 1 (self loop) ----------
__global__ void k_init_deg(float* __restrict__ deg) {
    int i = blockIdx.x * 256 + threadIdx.x;
    if (i < N_NODES) deg[i] = 1.0f;
}

// ---------- degree accumulate over edges (target = col = ei[E + e]) ----------
__global__ void k_deg(const int* __restrict__ ei, const int* __restrict__ flag,
                      float* __restrict__ deg) {
    int e = blockIdx.x * 256 + threadIdx.x;
    if (e >= NEDGE) return;
    int mode = flag[0];
    int dst = edge_at(ei, mode, NEDGE + e);
    atomicAdd(&deg[dst], 1.0f);
}

// ---------- dinv = rsqrt(deg), in place (deg >= 1 always) ----------
__global__ void k_dinv(float* __restrict__ deg) {
    int i = blockIdx.x * 256 + threadIdx.x;
    if (i < N_NODES) deg[i] = rsqrtf(deg[i]);
}

// ---------- xw = x @ W  (8 rows/block, thread = 4 cols via float4) ----------
__global__ void k_xw(const float* __restrict__ x, const float* __restrict__ W,
                     float* __restrict__ xw) {
    __shared__ float xs[8 * 128];
    int t = threadIdx.x;
    int rowBase = blockIdx.x * 8;
    {   // stage 8 rows of x (1024 floats) with float4
        int idx = t * 4;
        int r = idx >> 7;
        int rr = rowBase + r;
        float4_t v = {0.f, 0.f, 0.f, 0.f};
        if (rr < N_NODES) v = *(const float4_t*)&x[rr * 128 + (idx & 127)];
        *(float4_t*)&xs[idx] = v;
    }
    __syncthreads();
    int c = t & 31;          // col group (4 cols)
    int rloc = t >> 5;       // 0..7
    int row = rowBase + rloc;
    float4_t acc = {0.f, 0.f, 0.f, 0.f};
#pragma unroll 8
    for (int k = 0; k < 128; k++) {
        float xv = xs[rloc * 128 + k];
        float4_t wv = *(const float4_t*)&W[k * 128 + c * 4];
        acc += xv * wv;
    }
    if (row < N_NODES) *(float4_t*)&xw[row * 128 + c * 4] = acc;
}

// ---------- scatter: agg[dst] += dinv[src]*dinv[dst]*xw[src]  ----------
// thread = (edge, feature-group of 4); 32 threads per edge
__global__ void k_scatter(const int* __restrict__ ei, const int* __restrict__ flag,
                          const float* __restrict__ xw,
                          const float* __restrict__ dinv, float* __restrict__ agg) {
    unsigned tid = blockIdx.x * 256 + threadIdx.x;
    int e = tid >> 5;
    int g = tid & 31;
    if (e >= NEDGE) return;
    int mode = flag[0];
    int src = edge_at(ei, mode, e);
    int dst = edge_at(ei, mode, NEDGE + e);
    float w = dinv[src] * dinv[dst];
    float4_t v = *(const float4_t*)&xw[src * 128 + g * 4];
    v *= w;
    float* base = &agg[dst * 128 + g * 4];
    atomicAdd(base + 0, v.x);
    atomicAdd(base + 1, v.y);
    atomicAdd(base + 2, v.z);
    atomicAdd(base + 3, v.w);
}

// ---------- h = relu(dinv^2*xw + agg + b) -> bf16 ----------
__global__ void k_h(const float* __restrict__ xw, const float* __restrict__ agg,
                    const float* __restrict__ dinv, const float* __restrict__ b,
                    __hip_bfloat16* __restrict__ hbf) {
    int i = blockIdx.x * 256 + threadIdx.x;
    if (i >= N_NODES * NHID) return;
    int node = i >> 7, f = i & 127;
    float di = dinv[node];
    float v = di * di * xw[i] + agg[i] + b[f];
    v = fmaxf(v, 0.0f);
    hbf[i] = __float2bfloat16(v);
}

// ---------- out = h @ h^T  (128x128 tile per block, K=128 single pass) ----------
#define LDSLD 136   // 128 + 8 pad: stride = 68 dwords == 4 mod 32 -> 2-way (free)
__global__ __launch_bounds__(256, 2)
void k_gemm(const __hip_bfloat16* __restrict__ h, float* __restrict__ out) {
    __shared__ unsigned short As[128][LDSLD];
    __shared__ unsigned short Bs[128][LDSLD];
    int by = blockIdx.y, bx = blockIdx.x;
    int t = threadIdx.x;
    const unsigned short* hu = (const unsigned short*)h;

    // full tile = 128 rows x 16 col-groups of 8 shorts = 2048 slots; 256 thr x 8 it
#pragma unroll
    for (int it = 0; it < 8; it++) {
        int c = t + it * 256;        // 0..2047
        int row = c >> 4;            // 0..127
        int col8 = (c & 15) * 8;     // 0,8,...,120
        int gra = by * 128 + row;
        float4_t va = {0.f, 0.f, 0.f, 0.f};
        if (gra < N_NODES) va = *(const float4_t*)&hu[gra * 128 + col8];
        *(float4_t*)&As[row][col8] = va;
        int grb = bx * 128 + row;
        float4_t vb = {0.f, 0.f, 0.f, 0.f};
        if (grb < N_NODES) vb = *(const float4_t*)&hu[grb * 128 + col8];
        *(float4_t*)&Bs[row][col8] = vb;
    }
    __syncthreads();

    int lane = t & 63, w = t >> 6;
    int wm = (w >> 1) * 64, wn = (w & 1) * 64;
    int quad = lane >> 4, l16 = lane & 15;

    float4_t acc[4][4] = {};
    short8 a_frag[4], b_frag[4];

#pragma unroll
    for (int ks = 0; ks < 4; ks++) {
        int k0 = ks * 32 + quad * 8;
#pragma unroll
        for (int mi = 0; mi < 4; mi++)
            a_frag[mi] = *(const short8*)&As[wm + mi * 16 + l16][k0];
#pragma unroll
        for (int ni = 0; ni < 4; ni++)
            b_frag[ni] = *(const short8*)&Bs[wn + ni * 16 + l16][k0];
#pragma unroll
        for (int mi = 0; mi < 4; mi++)
#pragma unroll
            for (int ni = 0; ni < 4; ni++)
                acc[mi][ni] = __builtin_amdgcn_mfma_f32_16x16x32_bf16(
                    a_frag[mi], b_frag[ni], acc[mi][ni], 0, 0, 0);
    }

#pragma unroll
    for (int mi = 0; mi < 4; mi++) {
        int gr0 = by * 128 + wm + mi * 16 + quad * 4;
#pragma unroll
        for (int r = 0; r < 4; r++) {
            int grow = gr0 + r;
            if (grow >= N_NODES) continue;
            long rowoff = (long)grow * N_NODES;
#pragma unroll
            for (int ni = 0; ni < 4; ni++) {
                int gcol = bx * 128 + wn + ni * 16 + l16;
                if (gcol < N_NODES)
                    __builtin_nontemporal_store(acc[mi][ni][r], &out[rowoff + gcol]);
            }
        }
    }
}

extern "C" void kernel_launch(void* const* d_in, const int* in_sizes, int n_in,
                              void* d_out, int out_size, void* d_ws, size_t ws_size,
                              hipStream_t stream) {
    const float* x  = (const float*)d_in[0];
    const int*   ei = (const int*)d_in[1];
    const float* W  = (const float*)d_in[2];
    const float* b  = (const float*)d_in[3];
    float* out = (float*)d_out;

    char* ws = (char*)d_ws;
    // workspace layout (all offsets 256B aligned)
    float* xw  = (float*)(ws);                               // 5,120,000 B
    float* agg = (float*)(ws + 5120000);                     // 5,120,000 B
    float* deg = (float*)(ws + 10240000);                    // 40,000 B (deg->dinv in place)
    int*   flg = (int*)  (ws + 10280448);                    // 4 B
    __hip_bfloat16* hbf = (__hip_bfloat16*)(ws + 10280960);  // 2,560,000 B

    hipMemsetAsync(agg, 0, (size_t)N_NODES * NHID * sizeof(float), stream);
    k_detect<<<1, 256, 0, stream>>>(ei, flg);
    k_init_deg<<<(N_NODES + 255) / 256, 256, 0, stream>>>(deg);
    k_deg<<<(NEDGE + 255) / 256, 256, 0, stream>>>(ei, flg, deg);
    k_dinv<<<(N_NODES + 255) / 256, 256, 0, stream>>>(deg);
    k_xw<<<(N_NODES + 7) / 8, 256, 0, stream>>>(x, W, xw);
    k_scatter<<<(NEDGE * 32 + 255) / 256, 256, 0, stream>>>(ei, flg, xw, deg, agg);
    k_h<<<(N_NODES * NHID + 255) / 256, 256, 0, stream>>>(xw, agg, deg, b, hbf);
    dim3 g((N_NODES + 127) / 128, (N_NODES + 127) / 128);
    k_gemm<<<g, 256, 0, stream>>>(hbf, out);
}